// Round 4
// baseline (2507.903 us; speedup 1.0000x reference)
//
#include <hip/hip_runtime.h>
#include <math.h>

#define H 512
#define W 512
#define TBINS 180
#define RBINS 360
#define NPIX (H*W)
#define NCELL (TBINS*RBINS)

#define THETA_MIN (-1.5707963267948966f)
#define T_BIN ((float)(3.141592653589793 / 179.0))
#define R_MIN (-724.0773439350246f)
#define R_BIN ((float)(2.0 * 724.0773439350246 / 359.0))
#define THR_VAR 100.0f
#define NSIG 6.5f          // truncation window; tail mass < 1e-10 << 1.16e-2 budget

#define CAP 49152
#define RT 6               // rho tiles of 64 cols (6*64 = 384 >= 360)
#define VBLK 512           // vote block: 8 waves
#define TCELLS (TBINS*64)  // 11520 LDS cells / tile

__device__ __forceinline__ float phi_cdf(float z) {
    return 0.5f * erfcf(-0.70710678118654752f * z);
}

struct PixParams { float theta, rho, var_theta, var_rho; };

// Faithful to reference incl. row_s quirk (residual uses img[clip(hi+dx), wi]).
__device__ __forceinline__ PixParams compute_pixel(const float* __restrict__ img,
                                                   int hi, int wi) {
    int xm = max(hi - 1, 0), xp = min(hi + 1, H - 1);
    int ym = max(wi - 1, 0), yp = min(wi + 1, W - 1);
    const float* r0 = img + xm * W;
    const float* r1 = img + hi * W;
    const float* r2 = img + xp * W;
    float s00 = r0[ym], s01 = r0[wi], s02 = r0[yp];
    float s10 = r1[ym], s11 = r1[wi], s12 = r1[yp];
    float s20 = r2[ym], s21 = r2[wi], s22 = r2[yp];

    float alpha_s = (s20 + s21 + s22) - (s00 + s01 + s02);
    float beta_s  = (s02 + s12 + s22) - (s00 + s10 + s20);
    float gsum    = s00 + s01 + s02 + s10 + s11 + s12 + s20 + s21 + s22;

    float alpha = alpha_s * (1.0f / 6.0f) + 1e-6f;
    float beta  = beta_s  * (1.0f / 6.0f) + 1e-6f;
    float gamma = gsum * (1.0f / 9.0f);

    float cvals[3] = { s01, s11, s21 };
    float eps2 = 0.0f;
    #pragma unroll
    for (int ix = 0; ix < 3; ++ix) {
        float dx = (float)(ix - 1);
        float c = cvals[ix];
        #pragma unroll
        for (int iy = 0; iy < 3; ++iy) {
            float dy = (float)(iy - 1);
            float r = c - alpha * dy - beta * dx - gamma;
            eps2 += r * r;
        }
    }
    float noise_var = eps2 * (1.0f / 7.0f);
    float va = noise_var * (1.0f / 6.0f);
    float g2 = alpha * alpha + beta * beta;
    float var_theta = (beta * beta * va + alpha * alpha * va) / (g2 * g2);

    float theta = atanf(beta / alpha);
    float ct = cosf(theta), st = sinf(theta);
    float x = (float)hi, y = (float)wi;
    float rho = x * ct + y * st;
    float drho = -x * st + y * ct;

    PixParams pp;
    pp.theta = theta; pp.rho = rho; pp.var_theta = var_theta;
    pp.var_rho = drho * drho * var_theta;
    return pp;
}

__global__ void init_kernel(float* __restrict__ out, int* __restrict__ count) {
    int i = blockIdx.x * blockDim.x + threadIdx.x;
    if (i < NCELL) out[i] = 0.0f;
    if (i == 0) *count = 0;
}

__global__ void prep_kernel(const float* __restrict__ img,
                            const float* __restrict__ mask,
                            int* __restrict__ count,
                            float4* __restrict__ recs,
                            int4* __restrict__ aux) {
    int p = blockIdx.x * blockDim.x + threadIdx.x;
    if (p >= NPIX) return;
    int hi = p >> 9, wi = p & (W - 1);
    float mv = mask[p];
    PixParams pp = compute_pixel(img, hi, wi);
    if (!(pp.var_theta <= THR_VAR) || !(pp.var_rho <= THR_VAR) || mv == 0.0f)
        return;
    float sig_t = sqrtf(pp.var_theta + 1e-12f);
    float sig_r = sqrtf(pp.var_rho + 1e-12f);

    float radr = NSIG * sig_r;
    int rlo = (int)floorf((pp.rho - radr - R_MIN) / R_BIN - 0.5f);
    int rhi = (int)ceilf((pp.rho + radr - R_MIN) / R_BIN + 0.5f);
    rlo = max(rlo, 0); rhi = min(rhi, RBINS - 1);
    if (rhi < rlo) return;

    float radt = NSIG * sig_t;
    int tlo = (int)floorf((pp.theta - radt - THETA_MIN) / T_BIN - 0.5f);
    int thi = (int)ceilf((pp.theta + radt - THETA_MIN) / T_BIN + 0.5f);
    tlo = max(tlo, 0); thi = min(thi, TBINS - 1);

    int pos = atomicAdd(count, 1);
    if (pos < CAP) {
        float4 rc; rc.x = pp.theta; rc.y = 1.0f / sig_t; rc.z = pp.rho; rc.w = 1.0f / sig_r;
        recs[pos] = rc;
        int4 ax; ax.x = rlo | (rhi << 16); ax.y = tlo | (thi << 16);
        ax.z = __float_as_int(mv); ax.w = 0;
        aux[pos] = ax;
    }
}

// 8 waves/block; block privatizes a 180x64 rho-tile in LDS.
// Ballot-compacted entry scan; SLAB=true drains with plain stores to a
// private slab (no atomics), SLAB=false (tiny-ws fallback) atomically
// drains into out.
template <bool SLAB>
__global__ void __launch_bounds__(VBLK)
vote_kernel(const float4* __restrict__ recs,
            const int4* __restrict__ aux,
            const int* __restrict__ count,
            float* __restrict__ slabs,
            float* __restrict__ out,
            int CHv) {
    __shared__ float tile[TCELLS];
    __shared__ float ebuf[8 * 184];

    int rt = blockIdx.x % RT;
    int chunk = blockIdx.x / RT;
    int c0 = rt * 64;
    int wv = threadIdx.x >> 6, lane = threadIdx.x & 63;

    for (int k = threadIdx.x; k < TCELLS; k += VBLK) tile[k] = 0.0f;
    __syncthreads();

    int n = min(*count, CAP);
    float* eb = ebuf + wv * 184;
    int step = CHv * 8;

    for (int b = chunk * 8 + wv; b * 64 < n; b += step) {
        int idx = b * 64 + lane;
        int4 ax; float4 rc;
        int rlo = 1, rhi = 0;
        bool inb = idx < n;
        if (inb) {
            ax = aux[idx]; rc = recs[idx];
            rlo = ax.x & 0xffff; rhi = ax.x >> 16;
        }
        bool pred = inb && (rhi >= c0) && (rlo <= c0 + 63);
        unsigned long long m = __ballot(pred);
        while (m) {
            int j = __ffsll(m) - 1;
            m &= m - 1;
            float theta = __shfl(rc.x, j, 64);
            float ist   = __shfl(rc.y, j, 64);
            float rho   = __shfl(rc.z, j, 64);
            float isr   = __shfl(rc.w, j, 64);
            int   tw    = __shfl(ax.y, j, 64);
            float mv    = __shfl(__int_as_float(ax.z), j, 64);
            int tlo = tw & 0xffff, thi = tw >> 16;
            int ne = thi - tlo + 2;      // edge CDFs tlo..thi+1

            #pragma unroll
            for (int k = 0; k < 3; ++k) {
                int ei = lane + 64 * k;
                if (ei < ne) {
                    float edge = THETA_MIN + ((float)(tlo + ei) - 0.5f) * T_BIN;
                    eb[ei] = phi_cdf((edge - theta) * ist);
                }
            }

            int col = c0 + lane;
            float wr = 0.0f;
            if (col < RBINS) {
                float e0 = R_MIN + ((float)col - 0.5f) * R_BIN;
                wr = (phi_cdf((e0 + R_BIN - rho) * isr)
                    - phi_cdf((e0 - rho) * isr)) * mv;
            }

            float prev = eb[0];
            for (int t = tlo; t <= thi; ++t) {
                float cur = eb[t - tlo + 1];
                float w = (cur - prev) * wr;
                prev = cur;
                if (w != 0.0f)
                    atomicAdd(&tile[t * 64 + lane], w);
            }
        }
    }

    __syncthreads();

    if (SLAB) {
        // plain coalesced dwordx4 stores to this block's private slab
        float4* dst = (float4*)(slabs + (size_t)(rt * CHv + chunk) * TCELLS);
        const float4* src = (const float4*)tile;
        for (int k = threadIdx.x; k < TCELLS / 4; k += VBLK) dst[k] = src[k];
    } else {
        for (int k = threadIdx.x; k < TCELLS; k += VBLK) {
            float v = tile[k];
            if (v != 0.0f) {
                int t = k >> 6, cl = k & 63;
                int col = c0 + cl;
                if (col < RBINS) atomicAdd(&out[t * RBINS + col], v);
            }
        }
    }
}

__global__ void reduce_slab(const float* __restrict__ slabs,
                            float* __restrict__ out, int CHv) {
    int i = blockIdx.x * blockDim.x + threadIdx.x;
    if (i >= NCELL) return;
    int t = i / RBINS, col = i - t * RBINS;
    int rt = col >> 6, cl = col & 63;
    const float* base = slabs + (size_t)(rt * CHv) * TCELLS + t * 64 + cl;
    float s0 = 0.f, s1 = 0.f, s2 = 0.f, s3 = 0.f;
    int c = 0;
    for (; c + 4 <= CHv; c += 4) {
        s0 += base[(size_t)(c + 0) * TCELLS];
        s1 += base[(size_t)(c + 1) * TCELLS];
        s2 += base[(size_t)(c + 2) * TCELLS];
        s3 += base[(size_t)(c + 3) * TCELLS];
    }
    for (; c < CHv; ++c) s0 += base[(size_t)c * TCELLS];
    out[i] = (s0 + s1) + (s2 + s3);
}

extern "C" void kernel_launch(void* const* d_in, const int* in_sizes, int n_in,
                              void* d_out, int out_size, void* d_ws, size_t ws_size,
                              hipStream_t stream) {
    const float* img  = (const float*)d_in[0];
    const float* mask = (const float*)d_in[1];
    float* out = (float*)d_out;

    // ws: count@0 ; recs@256 (786432 B) ; aux (786432 B) ; slabs@1573120
    char* ws = (char*)d_ws;
    int*    count = (int*)ws;
    float4* recs  = (float4*)(ws + 256);
    int4*   aux   = (int4*)(ws + 256 + 786432);
    float*  slabs = (float*)(ws + 1573120);

    // pick chunk count from ws_size (host-side, constant -> graph-safe)
    int CHv = 0;
    const int cands[6] = {96, 64, 48, 32, 16, 8};
    for (int k = 0; k < 6; ++k) {
        size_t need = 1573120 + (size_t)RT * cands[k] * TCELLS * 4;
        if (need <= ws_size) { CHv = cands[k]; break; }
    }

    init_kernel<<<(NCELL + 255) / 256, 256, 0, stream>>>(out, count);
    prep_kernel<<<NPIX / 256, 256, 0, stream>>>(img, mask, count, recs, aux);
    if (CHv > 0) {
        vote_kernel<true><<<RT * CHv, VBLK, 0, stream>>>(recs, aux, count, slabs, out, CHv);
        reduce_slab<<<(NCELL + 255) / 256, 256, 0, stream>>>(slabs, out, CHv);
    } else {
        vote_kernel<false><<<RT * 16, VBLK, 0, stream>>>(recs, aux, count, slabs, out, 16);
    }
}

// Round 5
// 1699.035 us; speedup vs baseline: 1.4761x; 1.4761x over previous
//
#include <hip/hip_runtime.h>
#include <math.h>

#define H 512
#define W 512
#define TBINS 180
#define RBINS 360
#define NPIX (H*W)
#define NCELL (TBINS*RBINS)

#define THETA_MIN (-1.5707963267948966f)
#define T_BIN ((float)(3.141592653589793 / 179.0))
#define R_MIN (-724.0773439350246f)
#define R_BIN ((float)(2.0 * 724.0773439350246 / 359.0))
#define THR_VAR 100.0f
#define NSIG 6.5f          // tail mass < 1e-10, << 1.16e-2 budget (verified R4: absmax unchanged)

#define CAP 131072         // list capacity (n measured ~23.7k via FETCH_SIZE)
#define RT 6               // rho tiles of 64 cols
#define CH 24              // chunks per tile -> 144 vote blocks
#define VBLK 512           // 8 waves
#define TROWS 184          // padded theta-row stride
#define TCELLS (64*TROWS)  // 47104 B LDS tile, [col][row] layout

__device__ __forceinline__ float phi_cdf(float z) {
    return 0.5f * erfcf(-0.70710678118654752f * z);
}

struct PixParams { float theta, rho, var_theta, var_rho; };

// Faithful to reference incl. row_s quirk (residual uses img[clip(hi+dx), wi]).
__device__ __forceinline__ PixParams compute_pixel(const float* __restrict__ img,
                                                   int hi, int wi) {
    int xm = max(hi - 1, 0), xp = min(hi + 1, H - 1);
    int ym = max(wi - 1, 0), yp = min(wi + 1, W - 1);
    const float* r0 = img + xm * W;
    const float* r1 = img + hi * W;
    const float* r2 = img + xp * W;
    float s00 = r0[ym], s01 = r0[wi], s02 = r0[yp];
    float s10 = r1[ym], s11 = r1[wi], s12 = r1[yp];
    float s20 = r2[ym], s21 = r2[wi], s22 = r2[yp];

    float alpha_s = (s20 + s21 + s22) - (s00 + s01 + s02);
    float beta_s  = (s02 + s12 + s22) - (s00 + s10 + s20);
    float gsum    = s00 + s01 + s02 + s10 + s11 + s12 + s20 + s21 + s22;

    float alpha = alpha_s * (1.0f / 6.0f) + 1e-6f;
    float beta  = beta_s  * (1.0f / 6.0f) + 1e-6f;
    float gamma = gsum * (1.0f / 9.0f);

    float cvals[3] = { s01, s11, s21 };
    float eps2 = 0.0f;
    #pragma unroll
    for (int ix = 0; ix < 3; ++ix) {
        float dx = (float)(ix - 1);
        float c = cvals[ix];
        #pragma unroll
        for (int iy = 0; iy < 3; ++iy) {
            float dy = (float)(iy - 1);
            float r = c - alpha * dy - beta * dx - gamma;
            eps2 += r * r;
        }
    }
    float noise_var = eps2 * (1.0f / 7.0f);
    float va = noise_var * (1.0f / 6.0f);
    float g2 = alpha * alpha + beta * beta;
    float var_theta = (beta * beta * va + alpha * alpha * va) / (g2 * g2);

    float theta = atanf(beta / alpha);
    float ct = cosf(theta), st = sinf(theta);
    float x = (float)hi, y = (float)wi;
    float rho = x * ct + y * st;
    float drho = -x * st + y * ct;

    PixParams pp;
    pp.theta = theta; pp.rho = rho; pp.var_theta = var_theta;
    pp.var_rho = drho * drho * var_theta;
    return pp;
}

__global__ void init_kernel(float* __restrict__ out, int* __restrict__ count) {
    int i = blockIdx.x * blockDim.x + threadIdx.x;
    if (i < NCELL) out[i] = 0.0f;
    if (i == 0) *count = 0;
}

__global__ void prep_kernel(const float* __restrict__ img,
                            const float* __restrict__ mask,
                            int* __restrict__ count,
                            int* __restrict__ list) {
    int p = blockIdx.x * blockDim.x + threadIdx.x;
    if (p >= NPIX) return;
    int hi = p >> 9, wi = p & (W - 1);
    float mv = mask[p];
    PixParams pp = compute_pixel(img, hi, wi);
    if (!(pp.var_theta <= THR_VAR) || !(pp.var_rho <= THR_VAR) || mv == 0.0f)
        return;
    float sig_r = sqrtf(pp.var_rho + 1e-12f);
    float radr = NSIG * sig_r;
    int rlo = max((int)floorf((pp.rho - radr - R_MIN) / R_BIN - 0.5f), 0);
    int rhi = min((int)ceilf((pp.rho + radr - R_MIN) / R_BIN + 0.5f), RBINS - 1);
    if (rhi < rlo) return;   // rho window entirely outside accumulator
    int pos = atomicAdd(count, 1);
    if (pos < CAP) list[pos] = p;
}

// 8 waves/block; block privatizes a [64 cols][180 rows] rho-tile in LDS.
// Scan: lane-parallel param compute + ballot. Hit: lanes own theta rows
// (wt in 3 regs), serial loop over <=32-col rho window, shfl-broadcast wr.
// Drain: device atomics straight into d_out (no ws bulk traffic).
__global__ void __launch_bounds__(VBLK)
vote_kernel(const float* __restrict__ img,
            const float* __restrict__ mask,
            const int* __restrict__ list,
            const int* __restrict__ count,
            float* __restrict__ out) {
    __shared__ float tile[TCELLS];

    int rt = blockIdx.x % RT;
    int chunk = blockIdx.x / RT;
    int c0 = rt * 64;
    int wv = threadIdx.x >> 6, lane = threadIdx.x & 63;

    for (int k = threadIdx.x; k < TCELLS; k += VBLK) tile[k] = 0.0f;
    __syncthreads();

    int n = min(*count, CAP);
    int nbatch = (n + 63) >> 6;

    for (int b = chunk * 8 + wv; b < nbatch; b += CH * 8) {
        int idx = b * 64 + lane;
        float theta = 0.f, ist = 0.f, rho = 0.f, isr = 0.f, mv = 0.f;
        int rlo = 1, rhi = 0, tlo = 0, thi = -1;
        if (idx < n) {
            int p = list[idx];
            int hi = p >> 9, wi = p & (W - 1);
            PixParams pp = compute_pixel(img, hi, wi);
            mv = mask[p];
            float sig_t = sqrtf(pp.var_theta + 1e-12f);
            float sig_r = sqrtf(pp.var_rho + 1e-12f);
            theta = pp.theta; rho = pp.rho;
            ist = 1.0f / sig_t; isr = 1.0f / sig_r;
            float radr = NSIG * sig_r;
            rlo = max((int)floorf((rho - radr - R_MIN) / R_BIN - 0.5f), 0);
            rhi = min((int)ceilf((rho + radr - R_MIN) / R_BIN + 0.5f), RBINS - 1);
            float radt = NSIG * sig_t;
            tlo = max((int)floorf((theta - radt - THETA_MIN) / T_BIN - 0.5f), 0);
            thi = min((int)ceilf((theta + radt - THETA_MIN) / T_BIN + 0.5f), TBINS - 1);
        }
        bool pred = (rhi >= rlo) && (rhi >= c0) && (rlo <= c0 + 63) && (thi >= tlo);
        unsigned long long m = __ballot(pred);
        while (m) {
            int j = __ffsll(m) - 1;
            m &= m - 1;
            float th  = __shfl(theta, j, 64);
            float ist_j = __shfl(ist, j, 64);
            float rh  = __shfl(rho, j, 64);
            float isr_j = __shfl(isr, j, 64);
            float mvj = __shfl(mv, j, 64);
            int tl  = __shfl(tlo, j, 64);
            int th2 = __shfl(thi, j, 64);
            int rl  = __shfl(rlo, j, 64);
            int rh2 = __shfl(rhi, j, 64);

            int clo = max(rl - c0, 0);
            int chi = min(rh2 - c0, 63);
            int ncols = chi - clo + 1;

            // rho weight: lane -> col clo+lane (window <= 32 cols, fits wave)
            float wr = 0.0f;
            if (lane < ncols) {
                float e0 = R_MIN + ((float)(c0 + clo + lane) - 0.5f) * R_BIN;
                wr = (phi_cdf((e0 + R_BIN - rh) * isr_j)
                    - phi_cdf((e0 - rh) * isr_j)) * mvj;
            }

            // theta weights: lane owns rows tl+lane, +64, +128 (registers)
            float wt0 = 0.f, wt1 = 0.f, wt2 = 0.f;
            {
                int t = tl + lane;
                if (t <= th2) {
                    float e0 = THETA_MIN + ((float)t - 0.5f) * T_BIN;
                    wt0 = phi_cdf((e0 + T_BIN - th) * ist_j) - phi_cdf((e0 - th) * ist_j);
                }
            }
            if (tl + 64 <= th2) {        // wave-uniform guards
                int t = tl + 64 + lane;
                if (t <= th2) {
                    float e0 = THETA_MIN + ((float)t - 0.5f) * T_BIN;
                    wt1 = phi_cdf((e0 + T_BIN - th) * ist_j) - phi_cdf((e0 - th) * ist_j);
                }
            }
            if (tl + 128 <= th2) {
                int t = tl + 128 + lane;
                if (t <= th2) {
                    float e0 = THETA_MIN + ((float)t - 0.5f) * T_BIN;
                    wt2 = phi_cdf((e0 + T_BIN - th) * ist_j) - phi_cdf((e0 - th) * ist_j);
                }
            }
            bool a0 = wt0 != 0.f, a1 = wt1 != 0.f, a2 = wt2 != 0.f;

            for (int jj = 0; jj < ncols; ++jj) {
                float wrj = __shfl(wr, jj, 64);
                if (wrj == 0.0f) continue;
                int base = (clo + jj) * TROWS + tl + lane;
                if (a0) atomicAdd(&tile[base], wt0 * wrj);
                if (a1) atomicAdd(&tile[base + 64], wt1 * wrj);
                if (a2) atomicAdd(&tile[base + 128], wt2 * wrj);
            }
        }
    }

    __syncthreads();

    // drain straight to d_out (device-fast atomics), rotated start per block
    int startc = (int)(((unsigned)blockIdx.x * 2654435761u) >> 26) & 63;
    for (int cc = wv; cc < 64; cc += 8) {
        int col = cc + startc; if (col >= 64) col -= 64;
        int gcol = c0 + col;
        if (gcol >= RBINS) continue;
        #pragma unroll
        for (int k = 0; k < 3; ++k) {
            int r = lane + 64 * k;
            if (r < TBINS) {
                float v = tile[col * TROWS + r];
                if (v != 0.0f) atomicAdd(&out[r * RBINS + gcol], v);
            }
        }
    }
}

extern "C" void kernel_launch(void* const* d_in, const int* in_sizes, int n_in,
                              void* d_out, int out_size, void* d_ws, size_t ws_size,
                              hipStream_t stream) {
    const float* img  = (const float*)d_in[0];
    const float* mask = (const float*)d_in[1];
    float* out = (float*)d_out;

    // ws usage kept tiny (ws bulk BW measured ~10 GB/s — host-visible?):
    // count @0 ; list @256 (4 B * CAP = 512 KB)
    char* ws = (char*)d_ws;
    int* count = (int*)ws;
    int* list  = (int*)(ws + 256);

    init_kernel<<<(NCELL + 255) / 256, 256, 0, stream>>>(out, count);
    prep_kernel<<<NPIX / 256, 256, 0, stream>>>(img, mask, count, list);
    vote_kernel<<<RT * CH, VBLK, 0, stream>>>(img, mask, list, count, out);
}

// Round 6
// 198.299 us; speedup vs baseline: 12.6471x; 8.5680x over previous
//
#include <hip/hip_runtime.h>
#include <math.h>

#define H 512
#define W 512
#define TBINS 180
#define RBINS 360
#define NPIX (H*W)
#define NCELL (TBINS*RBINS)

#define THETA_MIN (-1.5707963267948966f)
#define T_BIN ((float)(3.141592653589793 / 179.0))
#define R_MIN (-724.0773439350246f)
#define R_BIN ((float)(2.0 * 724.0773439350246 / 359.0))
#define THR_VAR 100.0f
#define WSIG 6.0f          // bucket-membership window only; erfcf saturation makes fill exact

#define NT 6               // rho tiles (64 cols each)
#define KB 48              // k-blocks per tile -> 288 gemm blocks
#define BCAP 32768         // per-bucket capacity (expect <= ~15k)
#define MPAD 192           // theta rows padded 180 -> 192 (12 m-tiles of 16)

typedef short v8s __attribute__((ext_vector_type(8)));
typedef float v4f __attribute__((ext_vector_type(4)));

__device__ __forceinline__ float phi_cdf(float z) {
    return 0.5f * erfcf(-0.70710678118654752f * z);
}
__device__ __forceinline__ unsigned short f2bf(float f) {   // RNE f32->bf16
    unsigned u = __float_as_uint(f);
    return (unsigned short)((u + 0x7FFF + ((u >> 16) & 1)) >> 16);
}
__device__ __forceinline__ float bf2f(unsigned short b) {
    return __uint_as_float(((unsigned)b) << 16);
}

struct PixParams { float theta, rho, var_theta, var_rho; };

// Faithful to reference incl. row_s quirk (residual uses img[clip(hi+dx), wi]).
__device__ __forceinline__ PixParams compute_pixel(const float* __restrict__ img,
                                                   int hi, int wi) {
    int xm = max(hi - 1, 0), xp = min(hi + 1, H - 1);
    int ym = max(wi - 1, 0), yp = min(wi + 1, W - 1);
    const float* r0 = img + xm * W;
    const float* r1 = img + hi * W;
    const float* r2 = img + xp * W;
    float s00 = r0[ym], s01 = r0[wi], s02 = r0[yp];
    float s10 = r1[ym], s11 = r1[wi], s12 = r1[yp];
    float s20 = r2[ym], s21 = r2[wi], s22 = r2[yp];

    float alpha_s = (s20 + s21 + s22) - (s00 + s01 + s02);
    float beta_s  = (s02 + s12 + s22) - (s00 + s10 + s20);
    float gsum    = s00 + s01 + s02 + s10 + s11 + s12 + s20 + s21 + s22;

    float alpha = alpha_s * (1.0f / 6.0f) + 1e-6f;
    float beta  = beta_s  * (1.0f / 6.0f) + 1e-6f;
    float gamma = gsum * (1.0f / 9.0f);

    float cvals[3] = { s01, s11, s21 };
    float eps2 = 0.0f;
    #pragma unroll
    for (int ix = 0; ix < 3; ++ix) {
        float dx = (float)(ix - 1);
        float c = cvals[ix];
        #pragma unroll
        for (int iy = 0; iy < 3; ++iy) {
            float dy = (float)(iy - 1);
            float r = c - alpha * dy - beta * dx - gamma;
            eps2 += r * r;
        }
    }
    float noise_var = eps2 * (1.0f / 7.0f);
    float va = noise_var * (1.0f / 6.0f);
    float g2 = alpha * alpha + beta * beta;
    float var_theta = (beta * beta * va + alpha * alpha * va) / (g2 * g2);

    float theta = atanf(beta / alpha);
    float ct = cosf(theta), st = sinf(theta);
    float x = (float)hi, y = (float)wi;
    float rho = x * ct + y * st;
    float drho = -x * st + y * ct;

    PixParams pp;
    pp.theta = theta; pp.rho = rho; pp.var_theta = var_theta;
    pp.var_rho = drho * drho * var_theta;
    return pp;
}

__global__ void init_kernel(float* __restrict__ out, int* __restrict__ counts) {
    int i = blockIdx.x * blockDim.x + threadIdx.x;
    if (i < NCELL) out[i] = 0.0f;
    if (i < NT) counts[i] = 0;
}

__global__ void prep_kernel(const float* __restrict__ img,
                            const float* __restrict__ mask,
                            int* __restrict__ counts,
                            float4* __restrict__ recs,
                            float* __restrict__ mvs) {
    int p = blockIdx.x * blockDim.x + threadIdx.x;
    if (p >= NPIX) return;
    int hi = p >> 9, wi = p & (W - 1);
    float mv = mask[p];
    PixParams pp = compute_pixel(img, hi, wi);
    if (!(pp.var_theta <= THR_VAR) || !(pp.var_rho <= THR_VAR) || mv == 0.0f)
        return;
    float sig_t = sqrtf(pp.var_theta + 1e-12f);
    float sig_r = sqrtf(pp.var_rho + 1e-12f);
    float radr = WSIG * sig_r;
    int rlo = max((int)floorf((pp.rho - radr - R_MIN) / R_BIN - 0.5f), 0);
    int rhi = min((int)ceilf((pp.rho + radr - R_MIN) / R_BIN + 0.5f), RBINS - 1);
    if (rhi < rlo) return;                 // window misses accumulator entirely
    int nt0 = rlo >> 6, nt1 = rhi >> 6;    // 64-col tiles touched (1-2)
    float4 rc; rc.x = pp.theta; rc.y = 1.0f / sig_t; rc.z = pp.rho; rc.w = 1.0f / sig_r;
    for (int nt = nt0; nt <= nt1; ++nt) {
        int pos = atomicAdd(&counts[nt], 1);
        if (pos < BCAP) {
            recs[nt * BCAP + pos] = rc;
            mvs[nt * BCAP + pos] = mv;
        }
    }
}

// acc(t,c) = sum_p Wt[p][t] * Wr[p][c]  ==  GEMM  M=192(pad) N=64/tile K=pixels.
// bf16 hi/lo split inputs (3 MFMAs) keep input-quantization error ~1e-4.
// Zero records self-nullify (phi diff of equal args == 0).
__global__ void __launch_bounds__(512)
gemm_kernel(const float4* __restrict__ recs,
            const float* __restrict__ mvs,
            const int* __restrict__ counts,
            float* __restrict__ out) {
    __shared__ unsigned short Ah[MPAD * 32], Al[MPAD * 32]; // [m][k], k-contig
    __shared__ unsigned short Bh[64 * 32],  Bl[64 * 32];    // [n][k], k-contig
    __shared__ float4 prec[32];
    __shared__ float  pmv[32];

    int nt = blockIdx.x % NT, kb = blockIdx.x / NT;
    int tid = threadIdx.x;
    int lane = tid & 63, wv = tid >> 6;
    int nsub = wv & 3, mhalf = wv >> 2;     // wave -> 16-col subtile x 96-row half

    int cn = min(counts[nt], BCAP);
    int chunk = (cn + KB - 1) / KB;
    int k0 = kb * chunk, k1 = min(k0 + chunk, cn);

    v4f zero = {0.f, 0.f, 0.f, 0.f};
    v4f acc[6];
    #pragma unroll
    for (int i = 0; i < 6; ++i) acc[i] = zero;

    const float4* rb = recs + (size_t)nt * BCAP;
    const float*  mb = mvs + (size_t)nt * BCAP;
    int c0 = nt * 64;

    int slot = tid & 255;      // <192: A theta-row; >=192: B rho-col
    int pixpar = tid >> 8;     // pixel parity

    for (int ks = k0; ks < k1; ks += 32) {
        __syncthreads();       // protect LDS/prec from previous iteration's readers
        if (tid < 32) {
            int idx = ks + tid;
            if (idx < k1) { prec[tid] = rb[idx]; pmv[tid] = mb[idx]; }
            else {
                float4 z4; z4.x = 0.f; z4.y = 0.f; z4.z = 0.f; z4.w = 0.f;
                prec[tid] = z4; pmv[tid] = 0.f;
            }
        }
        __syncthreads();

        // fill: (pixel, slot) items; 16 per thread
        #pragma unroll 4
        for (int i = 0; i < 16; ++i) {
            int pix = pixpar + 2 * i;
            float4 rc = prec[pix];
            if (slot < MPAD) {
                float wt = 0.0f;
                if (slot < TBINS) {
                    float e0 = THETA_MIN + ((float)slot - 0.5f) * T_BIN;
                    wt = (phi_cdf((e0 + T_BIN - rc.x) * rc.y)
                        - phi_cdf((e0 - rc.x) * rc.y)) * pmv[pix];
                }
                unsigned short hb = f2bf(wt);
                Ah[slot * 32 + pix] = hb;
                Al[slot * 32 + pix] = f2bf(wt - bf2f(hb));
            } else {
                int n = slot - MPAD;
                float wr = 0.0f;
                if (c0 + n < RBINS) {
                    float e0 = R_MIN + ((float)(c0 + n) - 0.5f) * R_BIN;
                    wr = phi_cdf((e0 + R_BIN - rc.z) * rc.w)
                       - phi_cdf((e0 - rc.z) * rc.w);
                }
                unsigned short hb = f2bf(wr);
                Bh[n * 32 + pix] = hb;
                Bl[n * 32 + pix] = f2bf(wr - bf2f(hb));
            }
        }
        __syncthreads();

        // MFMA: A[m=lane&15][k=quad*8+j], B[n=lane&15][k=quad*8+j] (m120/m97 maps)
        int kq = (lane >> 4) * 8;
        int mr = lane & 15;
        v8s bh = *((__shared__ v8s*)&Bh[(nsub * 16 + mr) * 32 + kq]);
        v8s bl = *((__shared__ v8s*)&Bl[(nsub * 16 + mr) * 32 + kq]);
        #pragma unroll
        for (int mt = 0; mt < 6; ++mt) {
            int mbase = (mhalf * 6 + mt) * 16;
            v8s ah = *((__shared__ v8s*)&Ah[(mbase + mr) * 32 + kq]);
            v8s al = *((__shared__ v8s*)&Al[(mbase + mr) * 32 + kq]);
            acc[mt] = __builtin_amdgcn_mfma_f32_16x16x32_bf16(ah, bh, acc[mt], 0, 0, 0);
            acc[mt] = __builtin_amdgcn_mfma_f32_16x16x32_bf16(ah, bl, acc[mt], 0, 0, 0);
            acc[mt] = __builtin_amdgcn_mfma_f32_16x16x32_bf16(al, bh, acc[mt], 0, 0, 0);
        }
    }

    // drain: C/D layout col=lane&15 (n), row=(lane>>4)*4+reg (m)  [m89]
    int col = c0 + nsub * 16 + (lane & 15);
    if (col < RBINS) {
        int rq = (lane >> 4) * 4;
        #pragma unroll
        for (int mt = 0; mt < 6; ++mt) {
            int rbase = (mhalf * 6 + mt) * 16 + rq;
            #pragma unroll
            for (int r = 0; r < 4; ++r) {
                int row = rbase + r;
                float v = acc[mt][r];
                if (row < TBINS && v != 0.0f)
                    atomicAdd(&out[row * RBINS + col], v);
            }
        }
    }
}

extern "C" void kernel_launch(void* const* d_in, const int* in_sizes, int n_in,
                              void* d_out, int out_size, void* d_ws, size_t ws_size,
                              hipStream_t stream) {
    const float* img  = (const float*)d_in[0];
    const float* mask = (const float*)d_in[1];
    float* out = (float*)d_out;

    // ws (device memory, proven fast in R5): counts @0 (256 B pad);
    // recs: 6*32768*16 B = 3.146 MB ; mvs: 6*32768*4 B = 786 KB  (~4 MB total)
    char* ws = (char*)d_ws;
    int*    counts = (int*)ws;
    float4* recs   = (float4*)(ws + 256);
    float*  mvs    = (float*)(ws + 256 + (size_t)NT * BCAP * 16);

    init_kernel<<<(NCELL + 255) / 256, 256, 0, stream>>>(out, counts);
    prep_kernel<<<NPIX / 256, 256, 0, stream>>>(img, mask, counts, recs, mvs);
    gemm_kernel<<<NT * KB, 512, 0, stream>>>(recs, mvs, counts, out);
}

// Round 7
// 104.020 us; speedup vs baseline: 24.1097x; 1.9064x over previous
//
#include <hip/hip_runtime.h>
#include <math.h>

#define H 512
#define W 512
#define TBINS 180
#define RBINS 360
#define NPIX (H*W)
#define NCELL (TBINS*RBINS)

#define THETA_MIN (-1.5707963267948966f)
#define T_BIN ((float)(3.141592653589793 / 179.0))
#define R_MIN (-724.0773439350246f)
#define R_BIN ((float)(2.0 * 724.0773439350246 / 359.0))
#define THR_VAR 100.0f
#define WSIG 6.0f          // bucket-membership window; erfcf saturation keeps fill exact

#define NT 6               // rho tiles (64 cols each)
#define KB 32              // k-blocks per tile -> 192 gemm blocks
#define BCAP 32768
#define MPAD 192           // theta rows padded to 12 m-tiles of 16
#define PADC 32            // counts padded to 128 B apart (parallel atomic chains)

#define NEA 193            // theta edges (192 slots + 1)
#define NEB 65             // rho edges (64 slots + 1)
#define EST 33             // edge-row stride (pad 32->33: conflict-free)

typedef short v8s __attribute__((ext_vector_type(8)));
typedef float v4f __attribute__((ext_vector_type(4)));

__device__ __forceinline__ float phi_cdf(float z) {
    return 0.5f * erfcf(-0.70710678118654752f * z);
}
__device__ __forceinline__ unsigned short f2bf(float f) {   // RNE f32->bf16
    unsigned u = __float_as_uint(f);
    return (unsigned short)((u + 0x7FFF + ((u >> 16) & 1)) >> 16);
}
__device__ __forceinline__ float bf2f(unsigned short b) {
    return __uint_as_float(((unsigned)b) << 16);
}

struct PixParams { float theta, rho, var_theta, var_rho; };

// Faithful to reference incl. row_s quirk (residual uses img[clip(hi+dx), wi]).
__device__ __forceinline__ PixParams compute_pixel(const float* __restrict__ img,
                                                   int hi, int wi) {
    int xm = max(hi - 1, 0), xp = min(hi + 1, H - 1);
    int ym = max(wi - 1, 0), yp = min(wi + 1, W - 1);
    const float* r0 = img + xm * W;
    const float* r1 = img + hi * W;
    const float* r2 = img + xp * W;
    float s00 = r0[ym], s01 = r0[wi], s02 = r0[yp];
    float s10 = r1[ym], s11 = r1[wi], s12 = r1[yp];
    float s20 = r2[ym], s21 = r2[wi], s22 = r2[yp];

    float alpha_s = (s20 + s21 + s22) - (s00 + s01 + s02);
    float beta_s  = (s02 + s12 + s22) - (s00 + s10 + s20);
    float gsum    = s00 + s01 + s02 + s10 + s11 + s12 + s20 + s21 + s22;

    float alpha = alpha_s * (1.0f / 6.0f) + 1e-6f;
    float beta  = beta_s  * (1.0f / 6.0f) + 1e-6f;
    float gamma = gsum * (1.0f / 9.0f);

    float cvals[3] = { s01, s11, s21 };
    float eps2 = 0.0f;
    #pragma unroll
    for (int ix = 0; ix < 3; ++ix) {
        float dx = (float)(ix - 1);
        float c = cvals[ix];
        #pragma unroll
        for (int iy = 0; iy < 3; ++iy) {
            float dy = (float)(iy - 1);
            float r = c - alpha * dy - beta * dx - gamma;
            eps2 += r * r;
        }
    }
    float noise_var = eps2 * (1.0f / 7.0f);
    float va = noise_var * (1.0f / 6.0f);
    float g2 = alpha * alpha + beta * beta;
    float var_theta = (beta * beta * va + alpha * alpha * va) / (g2 * g2);

    float theta = atanf(beta / alpha);
    float ct = cosf(theta), st = sinf(theta);
    float x = (float)hi, y = (float)wi;
    float rho = x * ct + y * st;
    float drho = -x * st + y * ct;

    PixParams pp;
    pp.theta = theta; pp.rho = rho; pp.var_theta = var_theta;
    pp.var_rho = drho * drho * var_theta;
    return pp;
}

__global__ void init_kernel(float* __restrict__ out, int* __restrict__ counts) {
    int i = blockIdx.x * blockDim.x + threadIdx.x;
    if (i < NCELL) out[i] = 0.0f;
    if (i < NT * PADC) counts[i] = 0;
}

// Block-aggregated bucketing: LDS histogram -> 1 global atomic per bucket per
// block (padded counters). Records = 4 B pixel index only.
__global__ void prep_kernel(const float* __restrict__ img,
                            const float* __restrict__ mask,
                            int* __restrict__ counts,
                            int* __restrict__ list) {
    __shared__ int lcnt[NT], gbase[NT];
    int tid = threadIdx.x;
    if (tid < NT) lcnt[tid] = 0;
    __syncthreads();

    int p = blockIdx.x * blockDim.x + tid;   // grid covers NPIX exactly
    int hi = p >> 9, wi = p & (W - 1);
    float mv = mask[p];
    PixParams pp = compute_pixel(img, hi, wi);

    int myNt[2] = { -1, -1 };
    int myPos[2];
    bool valid = (pp.var_theta <= THR_VAR) && (pp.var_rho <= THR_VAR) && (mv != 0.0f);
    if (valid) {
        float sig_r = sqrtf(pp.var_rho + 1e-12f);
        float radr = WSIG * sig_r;
        int rlo = max((int)floorf((pp.rho - radr - R_MIN) / R_BIN - 0.5f), 0);
        int rhi = min((int)ceilf((pp.rho + radr - R_MIN) / R_BIN + 0.5f), RBINS - 1);
        if (rhi >= rlo) {
            int nt0 = rlo >> 6, nt1 = rhi >> 6;   // window < 64 bins -> <= 2 tiles
            for (int nt = nt0; nt <= nt1; ++nt) {
                int k = nt - nt0;
                myNt[k] = nt;
                myPos[k] = atomicAdd(&lcnt[nt], 1);
            }
        }
    }
    __syncthreads();
    if (tid < NT) {
        int c = lcnt[tid];
        gbase[tid] = c ? atomicAdd(&counts[tid * PADC], c) : 0;
    }
    __syncthreads();
    #pragma unroll
    for (int k = 0; k < 2; ++k) {
        if (myNt[k] >= 0) {
            int pos = gbase[myNt[k]] + myPos[k];
            if (pos < BCAP) list[myNt[k] * BCAP + pos] = p;
        }
    }
}

// acc(t,c) = sum_p Wt[p][t]*Wr[p][c] == GEMM M=192(pad) N=64/tile K=bucket.
// Params recomputed from pixel index (double-buffered, hidden under fill).
// Shared-edge CDF buffer halves erfcf count; bf16 hi/lo split -> 3 MFMAs.
__global__ void __launch_bounds__(512)
gemm_kernel(const float* __restrict__ img,
            const float* __restrict__ mask,
            const int* __restrict__ list,
            const int* __restrict__ counts,
            float* __restrict__ out) {
    __shared__ unsigned short Ah[MPAD * 32], Al[MPAD * 32]; // [m][k]
    __shared__ unsigned short Bh[64 * 32],  Bl[64 * 32];    // [n][k]
    __shared__ float EA[NEA * EST], EB[NEB * EST];          // edge CDFs [edge][pix]
    __shared__ float4 prec[2][32];
    __shared__ float  pmv[2][32];

    int nt = blockIdx.x % NT, kb = blockIdx.x / NT;
    int tid = threadIdx.x;
    int lane = tid & 63, wv = tid >> 6;
    int nsub = wv & 3, mhalf = wv >> 2;

    int cn = min(counts[nt * PADC], BCAP);
    int chunk = (cn + KB - 1) / KB;
    int k0 = kb * chunk, k1 = min(k0 + chunk, cn);

    v4f zero = {0.f, 0.f, 0.f, 0.f};
    v4f acc[6];
    #pragma unroll
    for (int i = 0; i < 6; ++i) acc[i] = zero;

    const int* lb = list + (size_t)nt * BCAP;
    int c0 = nt * 64;

    // prefetch chunk 0 params (tid<32; zero-fill -> phi diffs vanish)
    if (tid < 32) {
        int idx = k0 + tid;
        float4 rc; rc.x = 0.f; rc.y = 0.f; rc.z = 0.f; rc.w = 0.f;
        float mv = 0.f;
        if (idx < k1) {
            int p = lb[idx];
            PixParams pp = compute_pixel(img, p >> 9, p & (W - 1));
            mv = mask[p];
            rc.x = pp.theta; rc.y = 1.0f / sqrtf(pp.var_theta + 1e-12f);
            rc.z = pp.rho;   rc.w = 1.0f / sqrtf(pp.var_rho + 1e-12f);
        }
        prec[0][tid] = rc; pmv[0][tid] = mv;
    }

    int parity = 0;
    for (int ks = k0; ks < k1; ks += 32, parity ^= 1) {
        __syncthreads();
        if (tid < 32) {
            // prefetch next chunk's params while others fill edges
            int idx = ks + 32 + tid;
            if (ks + 32 < k1) {
                float4 rc; rc.x = 0.f; rc.y = 0.f; rc.z = 0.f; rc.w = 0.f;
                float mv = 0.f;
                if (idx < k1) {
                    int p = lb[idx];
                    PixParams pp = compute_pixel(img, p >> 9, p & (W - 1));
                    mv = mask[p];
                    rc.x = pp.theta; rc.y = 1.0f / sqrtf(pp.var_theta + 1e-12f);
                    rc.z = pp.rho;   rc.w = 1.0f / sqrtf(pp.var_rho + 1e-12f);
                }
                prec[parity ^ 1][tid] = rc; pmv[parity ^ 1][tid] = mv;
            }
        } else {
            // edge-CDF fill: (NEA+NEB)*32 = 8256 items over 480 threads
            for (int i = tid - 32; i < (NEA + NEB) * 32; i += 480) {
                int e = i >> 5, pix = i & 31;
                float4 rc = prec[parity][pix];
                if (e < NEA) {
                    float edge = THETA_MIN + ((float)e - 0.5f) * T_BIN;
                    EA[e * EST + pix] = phi_cdf((edge - rc.x) * rc.y);
                } else {
                    int n = e - NEA;
                    float edge = R_MIN + ((float)(c0 + n) - 0.5f) * R_BIN;
                    EB[n * EST + pix] = phi_cdf((edge - rc.z) * rc.w);
                }
            }
        }
        __syncthreads();

        // diff + bf16 hi/lo split; pix-minor so ds_write_b16 spreads banks
        {
            int pix = tid & 31, srow = tid >> 5;   // srow 0..15
            #pragma unroll
            for (int i = 0; i < 16; ++i) {
                int slot = srow + 16 * i;          // 0..255
                if (slot < MPAD) {
                    float wt = (EA[(slot + 1) * EST + pix] - EA[slot * EST + pix])
                             * pmv[parity][pix];
                    unsigned short hb = f2bf(wt);
                    Ah[slot * 32 + pix] = hb;
                    Al[slot * 32 + pix] = f2bf(wt - bf2f(hb));
                } else {
                    int n = slot - MPAD;
                    float wr = EB[(n + 1) * EST + pix] - EB[n * EST + pix];
                    unsigned short hb = f2bf(wr);
                    Bh[n * 32 + pix] = hb;
                    Bl[n * 32 + pix] = f2bf(wr - bf2f(hb));
                }
            }
        }
        __syncthreads();

        int kq = (lane >> 4) * 8;
        int mr = lane & 15;
        v8s bh = *((__shared__ v8s*)&Bh[(nsub * 16 + mr) * 32 + kq]);
        v8s bl = *((__shared__ v8s*)&Bl[(nsub * 16 + mr) * 32 + kq]);
        #pragma unroll
        for (int mt = 0; mt < 6; ++mt) {
            int mbase = (mhalf * 6 + mt) * 16;
            v8s ah = *((__shared__ v8s*)&Ah[(mbase + mr) * 32 + kq]);
            v8s al = *((__shared__ v8s*)&Al[(mbase + mr) * 32 + kq]);
            acc[mt] = __builtin_amdgcn_mfma_f32_16x16x32_bf16(ah, bh, acc[mt], 0, 0, 0);
            acc[mt] = __builtin_amdgcn_mfma_f32_16x16x32_bf16(ah, bl, acc[mt], 0, 0, 0);
            acc[mt] = __builtin_amdgcn_mfma_f32_16x16x32_bf16(al, bh, acc[mt], 0, 0, 0);
        }
    }

    // drain: C/D col=lane&15 (n), row=(lane>>4)*4+reg (m)  [verified R6]
    int col = c0 + nsub * 16 + (lane & 15);
    if (col < RBINS) {
        int rq = (lane >> 4) * 4;
        #pragma unroll
        for (int mt = 0; mt < 6; ++mt) {
            int rbase = (mhalf * 6 + mt) * 16 + rq;
            #pragma unroll
            for (int r = 0; r < 4; ++r) {
                int row = rbase + r;
                float v = acc[mt][r];
                if (row < TBINS && v != 0.0f)
                    atomicAdd(&out[row * RBINS + col], v);
            }
        }
    }
}

extern "C" void kernel_launch(void* const* d_in, const int* in_sizes, int n_in,
                              void* d_out, int out_size, void* d_ws, size_t ws_size,
                              hipStream_t stream) {
    const float* img  = (const float*)d_in[0];
    const float* mask = (const float*)d_in[1];
    float* out = (float*)d_out;

    // ws: counts @0 (NT*PADC ints = 768 B, padded chains) ; list @1024 (768 KB)
    char* ws = (char*)d_ws;
    int* counts = (int*)ws;
    int* list   = (int*)(ws + 1024);

    init_kernel<<<(NCELL + 255) / 256, 256, 0, stream>>>(out, counts);
    prep_kernel<<<NPIX / 256, 256, 0, stream>>>(img, mask, counts, list);
    gemm_kernel<<<NT * KB, 512, 0, stream>>>(img, mask, list, counts, out);
}